// Round 1
// baseline (1636.647 us; speedup 1.0000x reference)
//
#include <hip/hip_runtime.h>
#include <hip/hip_bf16.h>
#include <stdint.h>

// Problem constants
#define KDIM 4096   // IN_DIM
#define NDIM 4096   // OUT_DIM
#define MROWS 8192  // 4*2048
#define SEQ 2048
#define NBATCH 4

typedef __attribute__((ext_vector_type(8))) short short8;
typedef __attribute__((ext_vector_type(4))) float f32x4;

__device__ __forceinline__ float bf16_bits_to_f(uint32_t u16) {
  union { uint32_t u; float f; } c; c.u = u16 << 16; return c.f;
}
// Runtime-dual load: flag==1 -> storage is bf16, flag==0 -> f32
__device__ __forceinline__ float dload(const void* p, size_t idx, int flag) {
  if (flag) return bf16_bits_to_f(((const uint16_t*)p)[idx]);
  return ((const float*)p)[idx];
}
__device__ __forceinline__ uint16_t f2b(float f) {  // RNE f32->bf16
  union { float f; uint32_t u; } c; c.f = f;
  uint32_t b = c.u;
  return (uint16_t)((b + 0x7FFFu + ((b >> 16) & 1u)) >> 16);
}

// ---------------------------------------------------------------------------
// K0: dtype detection. Interpret first 512 bf16-slots of x. If storage is f32,
// ~half of these (low mantissa halves) decode to garbage exponents -> many
// |v|>1e3/NaN. If storage is bf16, all are ~N(0,1). Writes flag (1=bf16).
__global__ void k_detect(const uint16_t* xu, int* flag) {
  int lane = threadIdx.x;  // 64 threads, 1 wave
  int bad = 0;
  for (int i = lane; i < 512; i += 64) {
    float v = bf16_bits_to_f((uint32_t)xu[i]);
    if (!(v == v) || fabsf(v) > 1000.0f) bad++;
  }
  for (int off = 32; off > 0; off >>= 1) bad += __shfl_down(bad, off);
  if (lane == 0) *flag = (bad < 32) ? 1 : 0;
}

// ---------------------------------------------------------------------------
// K1: tiny precomputes.
//  W_combT[i][t] (bf16, padded to 16) = sum_r W_qkv[t][r] * W_down[r][i]
//  W_up_s[o][r] = W_up[o][r] * diag_b[o] * 4.0   (SCALING = 32/8)
//  b_pre_f[o]   = b_pre[o]
__global__ __launch_bounds__(256) void k_prep(
    const void* W_down, const void* W_qkv, const void* W_up,
    const void* diag_b, const void* b_pre,
    uint16_t* W_combT, float* W_up_s, float* b_pre_f, const int* flagp) {
  const int flag = *flagp;
  const int tid = blockIdx.x * 256 + threadIdx.x;  // 192*256 = 49152 = 12*4096
  const int tt = tid >> 12;      // 0..11
  const int i = tid & 4095;
  float s = 0.f;
#pragma unroll
  for (int r = 0; r < 8; ++r)
    s += dload(W_qkv, tt * 8 + r, flag) * dload(W_down, (size_t)r * 4096 + i, flag);
  W_combT[(size_t)i * 16 + tt] = f2b(s);
  if (tt == 0) {
    W_combT[(size_t)i * 16 + 12] = 0;
    W_combT[(size_t)i * 16 + 13] = 0;
    W_combT[(size_t)i * 16 + 14] = 0;
    W_combT[(size_t)i * 16 + 15] = 0;
  }
  if (tid < 32768)
    W_up_s[tid] = dload(W_up, tid, flag) * dload(diag_b, tid >> 3, flag) * 4.0f;
  if (tid < 4096)
    b_pre_f[tid] = dload(b_pre, tid, flag);
}

// ---------------------------------------------------------------------------
// K2: qkv[m][t] = sum_i x[m][i] * W_combT[i][t], one wave per row m.
__global__ __launch_bounds__(256) void k_qkv(const void* x, const uint16_t* Wc,
                                             float* qkv, const int* flagp) {
  const int flag = *flagp;
  const int wv = (int)((blockIdx.x * 256 + threadIdx.x) >> 6);  // row 0..8191
  const int lane = threadIdx.x & 63;
  float acc[12];
#pragma unroll
  for (int t = 0; t < 12; ++t) acc[t] = 0.f;
  const size_t xbase = (size_t)wv * KDIM;
  for (int i0 = 0; i0 < KDIM; i0 += 64) {
    const int i = i0 + lane;
    const float xv = dload(x, xbase + i, flag);
    const uint4* wp = (const uint4*)(Wc + (size_t)i * 16);
    const uint4 w0 = wp[0];
    const uint4 w1 = wp[1];
    acc[0] += xv * bf16_bits_to_f(w0.x & 0xFFFFu);
    acc[1] += xv * bf16_bits_to_f(w0.x >> 16);
    acc[2] += xv * bf16_bits_to_f(w0.y & 0xFFFFu);
    acc[3] += xv * bf16_bits_to_f(w0.y >> 16);
    acc[4] += xv * bf16_bits_to_f(w0.z & 0xFFFFu);
    acc[5] += xv * bf16_bits_to_f(w0.z >> 16);
    acc[6] += xv * bf16_bits_to_f(w0.w & 0xFFFFu);
    acc[7] += xv * bf16_bits_to_f(w0.w >> 16);
    acc[8] += xv * bf16_bits_to_f(w1.x & 0xFFFFu);
    acc[9] += xv * bf16_bits_to_f(w1.x >> 16);
    acc[10] += xv * bf16_bits_to_f(w1.y & 0xFFFFu);
    acc[11] += xv * bf16_bits_to_f(w1.y >> 16);
  }
#pragma unroll
  for (int t = 0; t < 12; ++t)
    for (int off = 32; off > 0; off >>= 1) acc[t] += __shfl_down(acc[t], off);
  if (lane == 0) {
#pragma unroll
    for (int t = 0; t < 12; ++t) qkv[(size_t)wv * 12 + t] = acc[t];
  }
}

// ---------------------------------------------------------------------------
// K3: per-batch attention (head dim 4) + fold W_o. One thread per q-row.
// scores bounded (|s| <~ 60) so exp without max-subtraction is safe in f32.
__global__ __launch_bounds__(256) void k_attn(const float* qkv, const void* W_o,
                                              float* a_o, const int* flagp) {
  const int flag = *flagp;
  __shared__ uint2 sk[SEQ];  // k rows, 4 x bf16 packed
  __shared__ uint2 sv[SEQ];  // v rows
  const int b = blockIdx.x >> 3;   // 32 blocks: 4 batches x 8 row-blocks
  const int rb = blockIdx.x & 7;
  for (int j = threadIdx.x; j < SEQ; j += 256) {
    const float* qr = qkv + ((size_t)b * SEQ + j) * 12;
    uint2 pk, pv;
    pk.x = (uint32_t)f2b(qr[4]) | ((uint32_t)f2b(qr[5]) << 16);
    pk.y = (uint32_t)f2b(qr[6]) | ((uint32_t)f2b(qr[7]) << 16);
    pv.x = (uint32_t)f2b(qr[8]) | ((uint32_t)f2b(qr[9]) << 16);
    pv.y = (uint32_t)f2b(qr[10]) | ((uint32_t)f2b(qr[11]) << 16);
    sk[j] = pk;
    sv[j] = pv;
  }
  __syncthreads();
  const size_t m = (size_t)b * SEQ + rb * 256 + threadIdx.x;
  const float* qr = qkv + m * 12;
  const float q0 = qr[0] * 0.5f, q1 = qr[1] * 0.5f;  // 1/sqrt(4) folded
  const float q2 = qr[2] * 0.5f, q3 = qr[3] * 0.5f;
  float l = 0.f, c0 = 0.f, c1 = 0.f, c2 = 0.f, c3 = 0.f;
  for (int j = 0; j < SEQ; ++j) {
    const uint2 kk = sk[j];  // LDS broadcast (all lanes same addr)
    const float k0 = bf16_bits_to_f(kk.x & 0xFFFFu);
    const float k1 = bf16_bits_to_f(kk.x >> 16);
    const float k2 = bf16_bits_to_f(kk.y & 0xFFFFu);
    const float k3 = bf16_bits_to_f(kk.y >> 16);
    const float s = q0 * k0 + q1 * k1 + q2 * k2 + q3 * k3;
    const float e = __expf(s);
    const uint2 vv = sv[j];
    l += e;
    c0 += e * bf16_bits_to_f(vv.x & 0xFFFFu);
    c1 += e * bf16_bits_to_f(vv.x >> 16);
    c2 += e * bf16_bits_to_f(vv.y & 0xFFFFu);
    c3 += e * bf16_bits_to_f(vv.y >> 16);
  }
  const float inv = 1.0f / l;
  c0 *= inv; c1 *= inv; c2 *= inv; c3 *= inv;
  float wo[32];
#pragma unroll
  for (int i = 0; i < 32; ++i) wo[i] = dload(W_o, i, flag);
#pragma unroll
  for (int r = 0; r < 8; ++r)
    a_o[m * 8 + r] = c0 * wo[r * 4 + 0] + c1 * wo[r * 4 + 1] +
                     c2 * wo[r * 4 + 2] + c3 * wo[r * 4 + 3];
}

// ---------------------------------------------------------------------------
// K4: main GEMM  C[m][n] = sum_k x[m][k]*W_pre[n][k]  + b_pre[n]
//                + sum_r a_o[m][r]*W_up_s[n][r]   (fused adapter epilogue)
// 128x128 tile, BK=64, 4 waves, each wave 4x4 of 16x16x32 bf16 MFMA.
__global__ __launch_bounds__(256) void k_gemm(
    const void* x, const void* w, const float* a_o, const float* W_up_s,
    const float* b_pre_f, void* out, const int* flagp) {
  const int flag = *flagp;
  __shared__ __align__(16) uint16_t sA[128 * 64];
  __shared__ __align__(16) uint16_t sB[128 * 64];
  const int t = threadIdx.x;
  const int bm = blockIdx.x & 63;   // 64 m-tiles
  const int bn = blockIdx.x >> 6;   // 32 n-tiles
  // staging map: thread covers (row = t>>1, cols (t&1)*32 .. +32)
  const int srow = t >> 1;
  const int scol = (t & 1) * 32;
  const size_t ga = ((size_t)(bm * 128 + srow)) * KDIM + scol;
  const size_t gb = ((size_t)(bn * 128 + srow)) * KDIM + scol;
  // wave/fragment map
  const int lane = t & 63;
  const int wid = t >> 6;
  const int wm = (wid & 1) * 64;
  const int wn = (wid >> 1) * 64;
  const int fr = lane & 15;          // fragment row (A: m, B: n)
  const int fk = (lane >> 4) * 8;    // fragment k offset
  f32x4 acc[4][4];
#pragma unroll
  for (int a = 0; a < 4; ++a)
#pragma unroll
    for (int bq = 0; bq < 4; ++bq) acc[a][bq] = (f32x4){0.f, 0.f, 0.f, 0.f};

  for (int k0 = 0; k0 < KDIM; k0 += 64) {
    __syncthreads();
    if (flag) {
      const uint16_t* gx = (const uint16_t*)x + ga + k0;
      const uint16_t* gw = (const uint16_t*)w + gb + k0;
#pragma unroll
      for (int c = 0; c < 4; ++c) {
        *(uint4*)&sA[srow * 64 + scol + c * 8] = *(const uint4*)(gx + c * 8);
        *(uint4*)&sB[srow * 64 + scol + c * 8] = *(const uint4*)(gw + c * 8);
      }
    } else {
      const float* gx = (const float*)x + ga + k0;
      const float* gw = (const float*)w + gb + k0;
#pragma unroll
      for (int c = 0; c < 4; ++c) {
        float4 xa = *(const float4*)(gx + c * 8);
        float4 xb = *(const float4*)(gx + c * 8 + 4);
        uint4 pk;
        pk.x = (uint32_t)f2b(xa.x) | ((uint32_t)f2b(xa.y) << 16);
        pk.y = (uint32_t)f2b(xa.z) | ((uint32_t)f2b(xa.w) << 16);
        pk.z = (uint32_t)f2b(xb.x) | ((uint32_t)f2b(xb.y) << 16);
        pk.w = (uint32_t)f2b(xb.z) | ((uint32_t)f2b(xb.w) << 16);
        *(uint4*)&sA[srow * 64 + scol + c * 8] = pk;
        float4 wa = *(const float4*)(gw + c * 8);
        float4 wb = *(const float4*)(gw + c * 8 + 4);
        uint4 pw;
        pw.x = (uint32_t)f2b(wa.x) | ((uint32_t)f2b(wa.y) << 16);
        pw.y = (uint32_t)f2b(wa.z) | ((uint32_t)f2b(wa.w) << 16);
        pw.z = (uint32_t)f2b(wb.x) | ((uint32_t)f2b(wb.y) << 16);
        pw.w = (uint32_t)f2b(wb.z) | ((uint32_t)f2b(wb.w) << 16);
        *(uint4*)&sB[srow * 64 + scol + c * 8] = pw;
      }
    }
    __syncthreads();
#pragma unroll
    for (int kk = 0; kk < 64; kk += 32) {
      short8 af[4], bfr[4];
#pragma unroll
      for (int mb = 0; mb < 4; ++mb)
        af[mb] = *(const short8*)&sA[(wm + mb * 16 + fr) * 64 + kk + fk];
#pragma unroll
      for (int nb = 0; nb < 4; ++nb)
        bfr[nb] = *(const short8*)&sB[(wn + nb * 16 + fr) * 64 + kk + fk];
#pragma unroll
      for (int mb = 0; mb < 4; ++mb)
#pragma unroll
        for (int nb = 0; nb < 4; ++nb)
          acc[mb][nb] = __builtin_amdgcn_mfma_f32_16x16x32_bf16(
              af[mb], bfr[nb], acc[mb][nb], 0, 0, 0);
    }
  }
  // Epilogue. C/D map (verified m89/m91): col = lane&15, row = (lane>>4)*4+reg
  const int rq = (lane >> 4) * 4;
#pragma unroll
  for (int nb = 0; nb < 4; ++nb) {
    const int gn = bn * 128 + wn + nb * 16 + fr;
    const float bp = b_pre_f[gn];
    const float4 u0 = *(const float4*)&W_up_s[(size_t)gn * 8];
    const float4 u1 = *(const float4*)&W_up_s[(size_t)gn * 8 + 4];
#pragma unroll
    for (int mb = 0; mb < 4; ++mb) {
#pragma unroll
      for (int r = 0; r < 4; ++r) {
        const int gm = bm * 128 + wm + mb * 16 + rq + r;
        const float4 a0 = *(const float4*)&a_o[(size_t)gm * 8];
        const float4 a1 = *(const float4*)&a_o[(size_t)gm * 8 + 4];
        float v = acc[mb][nb][r] + bp + a0.x * u0.x + a0.y * u0.y +
                  a0.z * u0.z + a0.w * u0.w + a1.x * u1.x + a1.y * u1.y +
                  a1.z * u1.z + a1.w * u1.w;
        const size_t oidx = (size_t)gm * NDIM + gn;
        if (flag) ((uint16_t*)out)[oidx] = f2b(v);
        else ((float*)out)[oidx] = v;
      }
    }
  }
}

// ---------------------------------------------------------------------------
extern "C" void kernel_launch(void* const* d_in, const int* in_sizes, int n_in,
                              void* d_out, int out_size, void* d_ws,
                              size_t ws_size, hipStream_t stream) {
  const void* x = d_in[0];       // [4,2048,4096]
  const void* W_pre = d_in[1];   // [4096,4096]
  const void* b_pre = d_in[2];   // [4096]
  const void* W_down = d_in[3];  // [8,4096]
  const void* W_qkv = d_in[4];   // [12,8]
  const void* W_o = d_in[5];     // [8,4]
  const void* W_up = d_in[6];    // [4096,8]
  const void* diag_b = d_in[7];  // [4096]

  char* ws = (char*)d_ws;
  int* flag_p = (int*)ws;                         // @0
  uint16_t* W_combT = (uint16_t*)(ws + 64);       // [4096][16] bf16, 131072 B
  float* qkv = (float*)(ws + 131136);             // [8192][12] f32, 393216 B
  float* a_o = (float*)(ws + 524352);             // [8192][8]  f32, 262144 B
  float* W_up_s = (float*)(ws + 786496);          // [4096][8]  f32, 131072 B
  float* b_pre_f = (float*)(ws + 917568);         // [4096]     f32, 16384 B

  k_detect<<<1, 64, 0, stream>>>((const uint16_t*)x, flag_p);
  k_prep<<<192, 256, 0, stream>>>(W_down, W_qkv, W_up, diag_b, b_pre, W_combT,
                                  W_up_s, b_pre_f, flag_p);
  k_qkv<<<2048, 256, 0, stream>>>(x, W_combT, qkv, flag_p);
  k_attn<<<32, 256, 0, stream>>>(qkv, W_o, a_o, flag_p);
  k_gemm<<<2048, 256, 0, stream>>>(x, W_pre, a_o, W_up_s, b_pre_f, d_out,
                                   flag_p);
}